// Round 16
// baseline (35.880 us; speedup 1.0000x reference)
//
#include <hip/hip_runtime.h>
#include <hip/hip_bf16.h>

#define B_ROWS 4096
#define DIMN 128
#define N2 8192
// z pre-scaled by sqrt(log2(e)/TEMP) so mfma output is already the exp2 arg
#define SQRT_CEXP 1.6986436f

using f32x4 = __attribute__((ext_vector_type(4))) float;
using i32x4 = __attribute__((ext_vector_type(4))) int;
using i32x8 = __attribute__((ext_vector_type(8))) int;
typedef long i64;

// f8f6f4-native tiled Z layout:
//   byte addr = Rtile*2048 + lane*32 + b,  lane = (k>>5)*16 + (row&15)
// = the 16x16x128 MFMA A/B fragment; load = 2x global_load_dwordx4.
//
// ASYNC-LOAD REGISTER RULE (R12/R13): no consumer/refill slot aliasing.
// VGPR-CAP RULE (R12/R15): NEVER set a min-waves launch bound on the
// hand-counted-vmcnt kernel — a forced 128-reg cap causes scratch spills,
// and spill VMEM ops silently corrupt the vmcnt arithmetic -> NaN.

// --- 1. normalize+scale+quantize into fragment layout; positives partials ---
// Block 0 also zeroes out[0] (kernel boundary orders it before finalize_k).
__global__ __launch_bounds__(256) void normpos_k(const float* __restrict__ emb_i,
                                                 const float* __restrict__ emb_j,
                                                 i64* __restrict__ zt,
                                                 float* __restrict__ pospart,
                                                 float* __restrict__ out) {
    const int t = threadIdx.x;
    if (blockIdx.x == 0 && t == 0) out[0] = 0.f;
    const int lr = t >> 4;          // local row / pair
    const int s  = t & 15;          // 8-float slice (k = s*8..s*8+7)
    const int p  = blockIdx.x * 16 + lr;
    const float4* ai = (const float4*)(emb_i + (size_t)p * DIMN + s * 8);
    const float4* bj = (const float4*)(emb_j + (size_t)p * DIMN + s * 8);
    float4 a0 = ai[0], a1 = ai[1];
    float4 b0 = bj[0], b1 = bj[1];
    float sa = a0.x*a0.x + a0.y*a0.y + a0.z*a0.z + a0.w*a0.w
             + a1.x*a1.x + a1.y*a1.y + a1.z*a1.z + a1.w*a1.w;
    float sb = b0.x*b0.x + b0.y*b0.y + b0.z*b0.z + b0.w*b0.w
             + b1.x*b1.x + b1.y*b1.y + b1.z*b1.z + b1.w*b1.w;
    float dp = a0.x*b0.x + a0.y*b0.y + a0.z*b0.z + a0.w*b0.w
             + a1.x*b1.x + a1.y*b1.y + a1.z*b1.z + a1.w*b1.w;
    #pragma unroll
    for (int d = 1; d < 16; d <<= 1) {
        sa += __shfl_xor(sa, d);
        sb += __shfl_xor(sb, d);
        dp += __shfl_xor(dp, d);
    }
    float ia = __builtin_amdgcn_rsqf(fmaxf(sa, 1e-24f));
    float ib = __builtin_amdgcn_rsqf(fmaxf(sb, 1e-24f));
    float fa = ia * SQRT_CEXP, fb = ib * SQRT_CEXP;

    int wa0 = __builtin_amdgcn_cvt_pk_fp8_f32(a0.x * fa, a0.y * fa, 0, false);
    wa0     = __builtin_amdgcn_cvt_pk_fp8_f32(a0.z * fa, a0.w * fa, wa0, true);
    int wa1 = __builtin_amdgcn_cvt_pk_fp8_f32(a1.x * fa, a1.y * fa, 0, false);
    wa1     = __builtin_amdgcn_cvt_pk_fp8_f32(a1.z * fa, a1.w * fa, wa1, true);
    i64 qa = ((i64)(unsigned)wa1 << 32) | (unsigned)wa0;
    int wb0 = __builtin_amdgcn_cvt_pk_fp8_f32(b0.x * fb, b0.y * fb, 0, false);
    wb0     = __builtin_amdgcn_cvt_pk_fp8_f32(b0.z * fb, b0.w * fb, wb0, true);
    int wb1 = __builtin_amdgcn_cvt_pk_fp8_f32(b1.x * fb, b1.y * fb, 0, false);
    wb1     = __builtin_amdgcn_cvt_pk_fp8_f32(b1.z * fb, b1.w * fb, wb1, true);
    i64 qb = ((i64)(unsigned)wb1 << 32) | (unsigned)wb0;

    // fragment slot: k-block gk = s>>2, i64-in-lane = s&3, lane = gk*16+lr
    const int slot = ((s >> 2) * 16 + lr) * 4 + (s & 3);
    zt[(size_t)blockIdx.x * 256 + slot] = qa;            // Rtile = b
    zt[(size_t)(256 + blockIdx.x) * 256 + slot] = qb;    // Rtile = 256+b

    __shared__ float red[16];
    if (s == 0) red[lr] = dp * ia * ib;
    __syncthreads();
    if (t == 0) {
        float x = 0.f;
        #pragma unroll
        for (int i = 0; i < 16; ++i) x += red[i];
        pospart[blockIdx.x] = x;
    }
}

// --- step epilogue: ps[m][j] += exp2(acc), optional diagonal mask ------------
template <bool MASK>
__device__ __forceinline__ void accum_step(const f32x4 (&acc)[4],
                                           float (&ps)[4][4],
                                           int rb, int cb, int rq, int fr) {
    #pragma unroll
    for (int m = 0; m < 4; ++m)
        #pragma unroll
        for (int j = 0; j < 4; ++j) {
            float e = __builtin_amdgcn_exp2f(acc[m][j]);
            if (MASK) {
                if (rb + m * 16 + rq + j == cb + fr) e = 0.f;
            }
            ps[m][j] += e;
        }
}

// --- 2. row-panel Gram: MX 16x16x128 MFMA, 64-row panels (128 FLOP/B) --------
// 1024 blocks x 256 thr, NO min-waves bound (natural VGPR alloc, no spill).
// Block b: 64-row panel b>>3, col-eighth b&7. Wave w: 16 steps of 16 cols
// (1 tile, 4 MFMA m-reps). R14-proven 2-slot flip: refill OTHER slot BEFORE
// the wait; vmcnt(2) steady state (2 loads in flight), never 0 mid-loop.
__global__ __launch_bounds__(256) void gram_k(const char* __restrict__ zt,
                                              float* __restrict__ rowpart) {
    const int t = threadIdx.x;
    const int lane = t & 63;
    const int w = t >> 6;               // 0..3
    const int p = blockIdx.x >> 3;      // 64-row panel, 0..127
    const int e = blockIdx.x & 7;       // col eighth
    const int rb = p * 64;
    const int fr = lane & 15;
    const int rq = (lane >> 4) * 4;

    const char* pa = zt + (size_t)(p * 4) * 2048 + lane * 32;
    const char* pb = zt + (size_t)(e * 64 + w * 16) * 2048 + lane * 32;

    // prologue: A (8 loads) + B slot0 (2 loads)
    i32x4 Alo[4], Ahi[4];
    #pragma unroll
    for (int m = 0; m < 4; ++m) {
        asm volatile("global_load_dwordx4 %0, %1, off"
                     : "=v"(Alo[m]) : "v"(pa + (size_t)m * 2048));
        asm volatile("global_load_dwordx4 %0, %1, off offset:16"
                     : "=v"(Ahi[m]) : "v"(pa + (size_t)m * 2048));
    }
    i32x4 Bl[2], Bh[2];
    asm volatile("global_load_dwordx4 %0, %1, off"           : "=v"(Bl[0]) : "v"(pb));
    asm volatile("global_load_dwordx4 %0, %1, off offset:16" : "=v"(Bh[0]) : "v"(pb));
    asm volatile("s_waitcnt vmcnt(2)" ::: "memory");    // A done; B0 in flight
    __builtin_amdgcn_sched_barrier(0);
    i32x8 A8[4];
    #pragma unroll
    for (int m = 0; m < 4; ++m)
        A8[m] = __builtin_shufflevector(Alo[m], Ahi[m], 0, 1, 2, 3, 4, 5, 6, 7);

    float ps[4][4] = {};
    #pragma unroll
    for (int s = 0; s < 16; ++s) {
        if (s < 15) {                   // refill OTHER slot, then wait
            const char* pn = pb + (size_t)(s + 1) * 2048;
            asm volatile("global_load_dwordx4 %0, %1, off"
                         : "=v"(Bl[(s + 1) & 1]) : "v"(pn));
            asm volatile("global_load_dwordx4 %0, %1, off offset:16"
                         : "=v"(Bh[(s + 1) & 1]) : "v"(pn));
            asm volatile("s_waitcnt vmcnt(2)" ::: "memory");  // slot s done, s+1 flying
        } else {
            asm volatile("s_waitcnt vmcnt(0)" ::: "memory");
        }
        __builtin_amdgcn_sched_barrier(0);                    // rule #18 fence

        i32x8 B8 = __builtin_shufflevector(Bl[s & 1], Bh[s & 1],
                                           0, 1, 2, 3, 4, 5, 6, 7);
        f32x4 acc[4] = {};
        __builtin_amdgcn_s_setprio(1);
        #pragma unroll
        for (int m = 0; m < 4; ++m)
            acc[m] = __builtin_amdgcn_mfma_scale_f32_16x16x128_f8f6f4(
                A8[m], B8, acc[m], 0, 0,             // cbsz=fp8, blgp=fp8
                0, 0x7f7f7f7f, 0, 0x7f7f7f7f);       // unit scales (e8m0=127)
        __builtin_amdgcn_s_setprio(0);

        const int cb = (e * 64 + w * 16 + s) * 16;
        if (cb >= rb && cb < rb + 64) accum_step<true >(acc, ps, rb, cb, rq, fr);
        else                          accum_step<false>(acc, ps, rb, cb, rq, fr);
    }

    // 16-lane reduce per row, cross-wave LDS reduce, store this eighth's part
    #pragma unroll
    for (int m = 0; m < 4; ++m)
        #pragma unroll
        for (int j = 0; j < 4; ++j) {
            float v = ps[m][j];
            #pragma unroll
            for (int d = 1; d < 16; d <<= 1) v += __shfl_xor(v, d);
            ps[m][j] = v;
        }
    __shared__ float red[4][64];
    if (fr == 0) {
        #pragma unroll
        for (int m = 0; m < 4; ++m)
            #pragma unroll
            for (int j = 0; j < 4; ++j)
                red[w][m * 16 + rq + j] = ps[m][j];
    }
    __syncthreads();
    if (t < 64)
        rowpart[e * N2 + rb + t] = red[0][t] + red[1][t] + red[2][t] + red[3][t];
}

// --- 3. finalize, distributed: 8 blocks x 1024 thr, atomicAdd into out -------
__global__ void finalize_k(const float* __restrict__ rowpart,
                           const float* __restrict__ pospart,
                           float* __restrict__ out) {
    const int t = threadIdx.x;
    const int r = blockIdx.x * 1024 + t;
    float d = 0.f;
    #pragma unroll
    for (int k = 0; k < 8; ++k) d += rowpart[k * N2 + r];
    float acc = __builtin_amdgcn_logf(d) * 0.6931471805599453f;   // ln
    if (blockIdx.x == 0 && t < 256) acc -= 4.0f * pospart[t];
    #pragma unroll
    for (int m = 32; m; m >>= 1) acc += __shfl_xor(acc, m);
    __shared__ float red[16];
    if ((t & 63) == 0) red[t >> 6] = acc;
    __syncthreads();
    if (t == 0) {
        float x = 0.f;
        #pragma unroll
        for (int i = 0; i < 16; ++i) x += red[i];
        atomicAdd(out, x * (1.0f / (2.0f * B_ROWS * 5.0f)));
    }
}

extern "C" void kernel_launch(void* const* d_in, const int* in_sizes, int n_in,
                              void* d_out, int out_size, void* d_ws, size_t ws_size,
                              hipStream_t stream) {
    const float* emb_i = (const float*)d_in[0];
    const float* emb_j = (const float*)d_in[1];
    i64* zt        = (i64*)d_ws;                                   // 1 MB tiled fp8
    float* rowpart = (float*)((char*)d_ws + (size_t)N2 * DIMN);    // 256 KB (8 parts)
    float* pospart = rowpart + 8 * N2;                             // 1 KB

    normpos_k<<<256, 256, 0, stream>>>(emb_i, emb_j, zt, pospart, (float*)d_out);
    gram_k<<<1024, 256, 0, stream>>>((const char*)zt, rowpart);
    finalize_k<<<8, 1024, 0, stream>>>(rowpart, pospart, (float*)d_out);
}

// Round 18
// 25.809 us; speedup vs baseline: 1.3902x; 1.3902x over previous
//
#include <hip/hip_runtime.h>
#include <hip/hip_bf16.h>

#define B_ROWS 4096
#define DIMN 128
#define N2 8192
// z pre-scaled by sqrt(log2(e)/TEMP) so mfma output is already the exp2 arg
#define SQRT_CEXP 1.6986436f

using f32x4 = __attribute__((ext_vector_type(4))) float;
using i32x4 = __attribute__((ext_vector_type(4))) int;
using i32x8 = __attribute__((ext_vector_type(8))) int;
typedef long i64;

// f8f6f4-native tiled Z layout:
//   byte addr = Rtile*2048 + lane*32 + b,  lane = (k>>5)*16 + (row&15)
// = the 16x16x128 MFMA A/B fragment; load = 2x global_load_dwordx4.
//
// CONSTRAINT WEB (R9..R17) for the hand-counted-vmcnt pipeline:
//  - the refill slot must never alias the slot consumed this step (2-slot flip)
//  - NEVER cap VGPR below the kernel's natural allocation: spills are VMEM ops
//    that corrupt the counted vmcnt -> NaN (R12/R15/R17)
//  - 64-row/1-tile-step shape naturally needs 204 VGPR -> unusable; the R14
//    32-row/2-tile-step shape fits under default bounds and passes. USE R14.

// --- 1. normalize+scale+quantize into fragment layout; positives partials ---
// Block 0 also zeroes out[0] (kernel boundary orders it before finalize_k).
__global__ __launch_bounds__(256) void normpos_k(const float* __restrict__ emb_i,
                                                 const float* __restrict__ emb_j,
                                                 i64* __restrict__ zt,
                                                 float* __restrict__ pospart,
                                                 float* __restrict__ out) {
    const int t = threadIdx.x;
    if (blockIdx.x == 0 && t == 0) out[0] = 0.f;
    const int lr = t >> 4;          // local row / pair
    const int s  = t & 15;          // 8-float slice (k = s*8..s*8+7)
    const int p  = blockIdx.x * 16 + lr;
    const float4* ai = (const float4*)(emb_i + (size_t)p * DIMN + s * 8);
    const float4* bj = (const float4*)(emb_j + (size_t)p * DIMN + s * 8);
    float4 a0 = ai[0], a1 = ai[1];
    float4 b0 = bj[0], b1 = bj[1];
    float sa = a0.x*a0.x + a0.y*a0.y + a0.z*a0.z + a0.w*a0.w
             + a1.x*a1.x + a1.y*a1.y + a1.z*a1.z + a1.w*a1.w;
    float sb = b0.x*b0.x + b0.y*b0.y + b0.z*b0.z + b0.w*b0.w
             + b1.x*b1.x + b1.y*b1.y + b1.z*b1.z + b1.w*b1.w;
    float dp = a0.x*b0.x + a0.y*b0.y + a0.z*b0.z + a0.w*b0.w
             + a1.x*b1.x + a1.y*b1.y + a1.z*b1.z + a1.w*b1.w;
    #pragma unroll
    for (int d = 1; d < 16; d <<= 1) {
        sa += __shfl_xor(sa, d);
        sb += __shfl_xor(sb, d);
        dp += __shfl_xor(dp, d);
    }
    float ia = __builtin_amdgcn_rsqf(fmaxf(sa, 1e-24f));
    float ib = __builtin_amdgcn_rsqf(fmaxf(sb, 1e-24f));
    float fa = ia * SQRT_CEXP, fb = ib * SQRT_CEXP;

    int wa0 = __builtin_amdgcn_cvt_pk_fp8_f32(a0.x * fa, a0.y * fa, 0, false);
    wa0     = __builtin_amdgcn_cvt_pk_fp8_f32(a0.z * fa, a0.w * fa, wa0, true);
    int wa1 = __builtin_amdgcn_cvt_pk_fp8_f32(a1.x * fa, a1.y * fa, 0, false);
    wa1     = __builtin_amdgcn_cvt_pk_fp8_f32(a1.z * fa, a1.w * fa, wa1, true);
    i64 qa = ((i64)(unsigned)wa1 << 32) | (unsigned)wa0;
    int wb0 = __builtin_amdgcn_cvt_pk_fp8_f32(b0.x * fb, b0.y * fb, 0, false);
    wb0     = __builtin_amdgcn_cvt_pk_fp8_f32(b0.z * fb, b0.w * fb, wb0, true);
    int wb1 = __builtin_amdgcn_cvt_pk_fp8_f32(b1.x * fb, b1.y * fb, 0, false);
    wb1     = __builtin_amdgcn_cvt_pk_fp8_f32(b1.z * fb, b1.w * fb, wb1, true);
    i64 qb = ((i64)(unsigned)wb1 << 32) | (unsigned)wb0;

    // fragment slot: k-block gk = s>>2, i64-in-lane = s&3, lane = gk*16+lr
    const int slot = ((s >> 2) * 16 + lr) * 4 + (s & 3);
    zt[(size_t)blockIdx.x * 256 + slot] = qa;            // Rtile = b
    zt[(size_t)(256 + blockIdx.x) * 256 + slot] = qb;    // Rtile = 256+b

    __shared__ float red[16];
    if (s == 0) red[lr] = dp * ia * ib;
    __syncthreads();
    if (t == 0) {
        float x = 0.f;
        #pragma unroll
        for (int i = 0; i < 16; ++i) x += red[i];
        pospart[blockIdx.x] = x;
    }
}

// --- step epilogue: ps[m][j] += sum_n exp2(acc), optional diagonal mask ------
template <bool MASK>
__device__ __forceinline__ void accum_step(const f32x4 (&acc)[2][2],
                                           float (&ps)[2][4],
                                           int rb, int cb, int rq, int fr) {
    #pragma unroll
    for (int m = 0; m < 2; ++m)
        #pragma unroll
        for (int n = 0; n < 2; ++n)
            #pragma unroll
            for (int j = 0; j < 4; ++j) {
                float e = __builtin_amdgcn_exp2f(acc[m][n][j]);
                if (MASK) {
                    if (rb + m * 16 + rq + j == cb + n * 16 + fr) e = 0.f;
                }
                ps[m][j] += e;
            }
}

// --- 2. row-panel Gram: MX 16x16x128 MFMA, R14-proven (byte-for-byte) --------
// 1024 blocks x 256 thr (4 waves). Block b: 32-row panel b>>2, col-quarter b&3.
// Wave w: 512 cols = 16 steps of 32 cols (2 tiles, 4 MFMA). 2-slot flip,
// refill the OTHER slot BEFORE the wait, vmcnt(4) steady state, never 0
// mid-loop, sched_barrier fences. Default bounds: natural VGPR, no spill.
__global__ __launch_bounds__(256) void gram_k(const char* __restrict__ zt,
                                              float* __restrict__ rowpart) {
    const int t = threadIdx.x;
    const int lane = t & 63;
    const int w = t >> 6;               // 0..3
    const int p = blockIdx.x >> 2;      // 32-row panel, 0..255
    const int e = blockIdx.x & 3;       // col quarter
    const int rb = p * 32;
    const int fr = lane & 15;
    const int rq = (lane >> 4) * 4;

    const char* pa = zt + (size_t)(p * 2) * 2048 + lane * 32;
    const char* pb = zt + (size_t)(e * 128 + w * 32) * 2048 + lane * 32;

    // prologue: A (4 loads) + B slot0 (4 loads)
    i32x4 Alo[2], Ahi[2];
    #pragma unroll
    for (int m = 0; m < 2; ++m) {
        asm volatile("global_load_dwordx4 %0, %1, off"
                     : "=v"(Alo[m]) : "v"(pa + (size_t)m * 2048));
        asm volatile("global_load_dwordx4 %0, %1, off offset:16"
                     : "=v"(Ahi[m]) : "v"(pa + (size_t)m * 2048));
    }
    i32x4 Blo[2][2], Bhi[2][2];
    #pragma unroll
    for (int n = 0; n < 2; ++n) {
        asm volatile("global_load_dwordx4 %0, %1, off"
                     : "=v"(Blo[0][n]) : "v"(pb + (size_t)n * 2048));
        asm volatile("global_load_dwordx4 %0, %1, off offset:16"
                     : "=v"(Bhi[0][n]) : "v"(pb + (size_t)n * 2048));
    }
    asm volatile("s_waitcnt vmcnt(4)" ::: "memory");    // A done; B0 in flight
    __builtin_amdgcn_sched_barrier(0);
    i32x8 A8[2];
    #pragma unroll
    for (int m = 0; m < 2; ++m)
        A8[m] = __builtin_shufflevector(Alo[m], Ahi[m], 0, 1, 2, 3, 4, 5, 6, 7);

    float ps[2][4] = {};
    #pragma unroll
    for (int s = 0; s < 16; ++s) {
        if (s < 15) {                   // refill OTHER slot, then wait (R14 order)
            const char* pn = pb + (size_t)(s + 1) * 4096;
            #pragma unroll
            for (int n = 0; n < 2; ++n) {
                asm volatile("global_load_dwordx4 %0, %1, off"
                             : "=v"(Blo[(s + 1) & 1][n]) : "v"(pn + (size_t)n * 2048));
                asm volatile("global_load_dwordx4 %0, %1, off offset:16"
                             : "=v"(Bhi[(s + 1) & 1][n]) : "v"(pn + (size_t)n * 2048));
            }
            asm volatile("s_waitcnt vmcnt(4)" ::: "memory");  // slot s done, s+1 flying
        } else {
            asm volatile("s_waitcnt vmcnt(0)" ::: "memory");
        }
        __builtin_amdgcn_sched_barrier(0);                    // rule #18 fence

        f32x4 acc[2][2] = {};
        __builtin_amdgcn_s_setprio(1);
        #pragma unroll
        for (int n = 0; n < 2; ++n) {
            i32x8 B8 = __builtin_shufflevector(Blo[s & 1][n], Bhi[s & 1][n],
                                               0, 1, 2, 3, 4, 5, 6, 7);
            #pragma unroll
            for (int m = 0; m < 2; ++m)
                acc[m][n] = __builtin_amdgcn_mfma_scale_f32_16x16x128_f8f6f4(
                    A8[m], B8, acc[m][n], 0, 0,          // cbsz=fp8, blgp=fp8
                    0, 0x7f7f7f7f, 0, 0x7f7f7f7f);       // unit scales (e8m0=127)
        }
        __builtin_amdgcn_s_setprio(0);

        const int cb = e * 2048 + w * 512 + s * 32;
        if (cb == rb) accum_step<true >(acc, ps, rb, cb, rq, fr);
        else          accum_step<false>(acc, ps, rb, cb, rq, fr);
    }

    // 16-lane reduce per row, cross-wave LDS reduce, store this quarter's part
    #pragma unroll
    for (int m = 0; m < 2; ++m)
        #pragma unroll
        for (int j = 0; j < 4; ++j) {
            float v = ps[m][j];
            #pragma unroll
            for (int d = 1; d < 16; d <<= 1) v += __shfl_xor(v, d);
            ps[m][j] = v;
        }
    __shared__ float red[4][32];
    if (fr == 0) {
        #pragma unroll
        for (int m = 0; m < 2; ++m)
            #pragma unroll
            for (int j = 0; j < 4; ++j)
                red[w][m * 16 + rq + j] = ps[m][j];
    }
    __syncthreads();
    if (t < 32)
        rowpart[e * N2 + rb + t] = red[0][t] + red[1][t] + red[2][t] + red[3][t];
}

// --- 3. finalize, distributed: 8 blocks x 1024 thr, atomicAdd into out -------
__global__ void finalize_k(const float* __restrict__ rowpart,
                           const float* __restrict__ pospart,
                           float* __restrict__ out) {
    const int t = threadIdx.x;
    const int r = blockIdx.x * 1024 + t;
    float d = rowpart[r] + rowpart[N2 + r] + rowpart[2 * N2 + r] + rowpart[3 * N2 + r];
    float acc = __builtin_amdgcn_logf(d) * 0.6931471805599453f;   // ln
    if (blockIdx.x == 0 && t < 256) acc -= 4.0f * pospart[t];
    #pragma unroll
    for (int m = 32; m; m >>= 1) acc += __shfl_xor(acc, m);
    __shared__ float red[16];
    if ((t & 63) == 0) red[t >> 6] = acc;
    __syncthreads();
    if (t == 0) {
        float x = 0.f;
        #pragma unroll
        for (int i = 0; i < 16; ++i) x += red[i];
        atomicAdd(out, x * (1.0f / (2.0f * B_ROWS * 5.0f)));
    }
}

extern "C" void kernel_launch(void* const* d_in, const int* in_sizes, int n_in,
                              void* d_out, int out_size, void* d_ws, size_t ws_size,
                              hipStream_t stream) {
    const float* emb_i = (const float*)d_in[0];
    const float* emb_j = (const float*)d_in[1];
    i64* zt        = (i64*)d_ws;                                   // 1 MB tiled fp8
    float* rowpart = (float*)((char*)d_ws + (size_t)N2 * DIMN);    // 128 KB (4 parts)
    float* pospart = rowpart + 4 * N2;                             // 1 KB

    normpos_k<<<256, 256, 0, stream>>>(emb_i, emb_j, zt, pospart, (float*)d_out);
    gram_k<<<1024, 256, 0, stream>>>((const char*)zt, rowpart);
    finalize_k<<<8, 1024, 0, stream>>>(rowpart, pospart, (float*)d_out);
}